// Round 2
// baseline (129.723 us; speedup 1.0000x reference)
//
#include <hip/hip_runtime.h>

#define NQ 8
#define BINS 256
#define D 128
#define RPB 16            // rows per block
#define THREADS 512       // 8 waves; grid 512 -> 2 blocks/CU sliding
#define RSTRIDE 132       // prep staging stride
#define FREG 520          // shorts per frag region (512 + 8 pad)

typedef short s8v __attribute__((ext_vector_type(8)));   // 8 bf16 in 4 VGPRs
typedef short s4v __attribute__((ext_vector_type(4)));   // 4 bf16 in 2 VGPRs
typedef float f4v __attribute__((ext_vector_type(4)));   // MFMA accumulator

static __device__ __forceinline__ unsigned short bf16_rtne(float x) {
    unsigned u = __float_as_uint(x);
    unsigned r = (u + 0x7fffu + ((u >> 16) & 1u)) >> 16;
    return (unsigned short)r;
}
static __device__ __forceinline__ float bf16_to_f(unsigned short h) {
    return __uint_as_float(((unsigned)h) << 16);
}
struct Split3 { short h, m, l; };
static __device__ __forceinline__ Split3 split3(float x) {
    Split3 s;
    unsigned short hb = bf16_rtne(x);
    float r1 = x - bf16_to_f(hb);
    unsigned short mb = bf16_rtne(r1);
    unsigned short lb = bf16_rtne(r1 - bf16_to_f(mb));
    s.h = (short)hb; s.m = (short)mb; s.l = (short)lb;
    return s;
}
static __device__ __forceinline__ unsigned long long u64min(unsigned long long a, unsigned long long b) {
    return a < b ? a : b;
}
// min over the 16-lane DPP row (pure VALU): xor1, xor2 via quad_perm, then ror4, ror8
static __device__ __forceinline__ unsigned dpp_row_min16(unsigned v) {
    unsigned t;
    t = (unsigned)__builtin_amdgcn_update_dpp(0, (int)v, 0xB1,  0xF, 0xF, true); v = v < t ? v : t;
    t = (unsigned)__builtin_amdgcn_update_dpp(0, (int)v, 0x4E,  0xF, 0xF, true); v = v < t ? v : t;
    t = (unsigned)__builtin_amdgcn_update_dpp(0, (int)v, 0x124, 0xF, 0xF, true); v = v < t ? v : t;
    t = (unsigned)__builtin_amdgcn_update_dpp(0, (int)v, 0x128, 0xF, 0xF, true); v = v < t ? v : t;
    return v;
}

// ---- prep: codebooks fp32 -> bf16 3-way split (swizzled [L][kchunk][bin][8]) + ||c||^2 ----
__global__ __launch_bounds__(256) void rvq_prep(
    const float* __restrict__ cb, short* __restrict__ cb_hi,
    short* __restrict__ cb_mid, short* __restrict__ cb_lo,
    float* __restrict__ c2)
{
    __shared__ float st[16 * RSTRIDE];
    const int L = blockIdx.x >> 4;
    const int o = blockIdx.x & 15;
    const int t = threadIdx.x;

    const float4* src = (const float4*)(cb + ((size_t)L * BINS + o * 16) * D);
    #pragma unroll
    for (int i = 0; i < 2; ++i) {
        int f4 = i * 256 + t;
        int row = f4 >> 5, c4 = f4 & 31;
        float4 v = src[f4];
        float* d = &st[row * RSTRIDE + c4 * 4];
        d[0] = v.x; d[1] = v.y; d[2] = v.z; d[3] = v.w;
    }
    __syncthreads();

    const int bin = t >> 4;
    const int kc  = t & 15;
    const float* p = &st[bin * RSTRIDE + kc * 8];
    s8v h8, m8, l8;
    float s = 0.f;
    #pragma unroll
    for (int j = 0; j < 8; ++j) {
        float x = p[j];
        Split3 sp = split3(x);
        h8[j] = sp.h; m8[j] = sp.m; l8[j] = sp.l;
        s = fmaf(x, x, s);
    }
    int idx = (L * 16 + kc) * BINS + (o * 16 + bin);
    ((s8v*)cb_hi)[idx]  = h8;
    ((s8v*)cb_mid)[idx] = m8;
    ((s8v*)cb_lo)[idx]  = l8;
    s += __shfl_xor(s, 1, 64);
    s += __shfl_xor(s, 2, 64);
    s += __shfl_xor(s, 4, 64);
    s += __shfl_xor(s, 8, 64);
    if (kc == 0) c2[L * BINS + o * 16 + bin] = s;
}

// frag store: thread owns (row rr_, kchunk g8, half). Bank math (RPB=16 mapping):
// dword = 260*ks + 4*idx16 + 2*half -> bank = 4*((ks+rr_+4q)&7) + 2*half.
// Per wave (rr_ in {2w,2w+1}, gd 0..31): exactly 4 lanes per bank-pair = b64 minimum.
static __device__ __forceinline__ void frag_store4(
    const float* rres, short* ah, short* am, short* al, int rr_, int g8, int half)
{
    s4v h4, m4, l4;
    #pragma unroll
    for (int j = 0; j < 4; ++j) {
        Split3 sp = split3(rres[j]);
        h4[j] = sp.h; m4[j] = sp.m; l4[j] = sp.l;
    }
    int q = g8 & 3;
    int reg = g8 >> 2;                               // ks region (mt gone: RPB=16)
    int idx16 = q * 16 + ((rr_ + 4 * q) & 15);
    int off = reg * FREG + idx16 * 8 + half * 4;
    *(s4v*)&ah[off] = h4;
    *(s4v*)&am[off] = m4;
    *(s4v*)&al[off] = l4;
}

static __device__ __forceinline__ void issue_b(
    int lv, int bin, int quad,
    const s8v* __restrict__ bhp, const s8v* __restrict__ bmp, const s8v* __restrict__ blp,
    const float* __restrict__ c2p,
    s8v bh[4], s8v bm[4], s8v bl[4], float& c2v)
{
    c2v = c2p[lv * BINS + bin];
    #pragma unroll
    for (int ks = 0; ks < 4; ++ks) {
        int idx = (lv * 16 + ks * 4 + quad) * BINS + bin;
        bh[ks] = bhp[idx];
        bm[ks] = bmp[idx];
        bl[ks] = blp[idx];
    }
}

// ---- main: 16 rows/block, 8 waves, wave owns 32 bins (nt=2); residual in registers ----
__global__ __launch_bounds__(THREADS, 4) void rvq_kernel(
    const float* __restrict__ hidden,     // [N, D]
    const float* __restrict__ cb_f32,     // [NQ, BINS, D]
    const short* __restrict__ cb_hi,
    const short* __restrict__ cb_mid,
    const short* __restrict__ cb_lo,
    const float* __restrict__ c2p,        // [NQ, BINS]
    float* __restrict__ out_codes,        // [NQ, N] as float
    float* __restrict__ out_quant,        // [N, D]
    int N)
{
    __shared__ __align__(16) short ah[4 * FREG];
    __shared__ __align__(16) short am[4 * FREG];
    __shared__ __align__(16) short al[4 * FREG];
    __shared__ __align__(16) unsigned long long redw[RPB][10];  // 80B rows: 16B-aligned, 20-dword stride

    const int t = threadIdx.x;
    const int w = t >> 6;                 // wave 0..7
    const int l = t & 63;
    const int quad = l >> 4;
    const int m = l & 15;
    const int row0 = blockIdx.x * RPB;
    const int woff = w * 32;              // this wave's 32-bin window
    const int rr_  = t >> 5;              // owned row 0..15
    const int gd   = t & 31;
    const int g8   = gd >> 1;             // owned k-chunk 0..15
    const int half = gd & 1;
    const int dbase = g8 * 8 + half * 4;  // first owned dim (t*4: coalesced)

    // residual in registers: thread owns row rr_, dims [dbase, dbase+4)
    float rres[4];
    {
        const float4* hp = (const float4*)(hidden + (size_t)(row0 + rr_) * D + dbase);
        float4 v = *hp;
        rres[0] = v.x; rres[1] = v.y; rres[2] = v.z; rres[3] = v.w;
    }
    frag_store4(rres, ah, am, al, rr_, g8, half);

    const s8v* bhp = (const s8v*)cb_hi;
    const s8v* bmp = (const s8v*)cb_mid;
    const s8v* blp = (const s8v*)cb_lo;

    s8v bh[4], bm[4], bl[4];
    float c2v;
    issue_b(0, woff + m, quad, bhp, bmp, blp, c2p, bh, bm, bl, c2v);  // B(0, nt0) in flight

    for (int level = 0; level < NQ; ++level) {
        __syncthreads();   // frag stores visible; prefetched B complete (barrier drains vmcnt)

        // ---- A fragments: 12 x b128, balanced swizzle (8 lanes per bank-quad = min) ----
        s8v afh[4], afm[4], afl[4];
        {
            const int idx16 = quad * 16 + ((m + 4 * quad) & 15);
            #pragma unroll
            for (int ks = 0; ks < 4; ++ks) {
                int off = ks * FREG + idx16 * 8;
                afh[ks] = *(const s8v*)&ah[off];
                afm[ks] = *(const s8v*)&am[off];
                afl[ks] = *(const s8v*)&al[off];
            }
        }

        unsigned vkey[2][4];
        #pragma unroll
        for (int nt = 0; nt < 2; ++nt) {
            f4v a0 = {0.f, 0.f, 0.f, 0.f};   // hh
            f4v a1 = {0.f, 0.f, 0.f, 0.f};   // hm + mh
            f4v a2 = {0.f, 0.f, 0.f, 0.f};   // mm + hl + lh
            #pragma unroll
            for (int ks = 0; ks < 4; ++ks) {
                a0 = __builtin_amdgcn_mfma_f32_16x16x32_bf16(afh[ks], bh[ks], a0, 0, 0, 0);
                a1 = __builtin_amdgcn_mfma_f32_16x16x32_bf16(afh[ks], bm[ks], a1, 0, 0, 0);
                a1 = __builtin_amdgcn_mfma_f32_16x16x32_bf16(afm[ks], bh[ks], a1, 0, 0, 0);
                a2 = __builtin_amdgcn_mfma_f32_16x16x32_bf16(afm[ks], bm[ks], a2, 0, 0, 0);
                a2 = __builtin_amdgcn_mfma_f32_16x16x32_bf16(afh[ks], bl[ks], a2, 0, 0, 0);
                a2 = __builtin_amdgcn_mfma_f32_16x16x32_bf16(afl[ks], bh[ks], a2, 0, 0, 0);
            }
            float c2cur = c2v;
            if (nt == 0)   // nt1 B loads overlap nt0 key-compute (WAR on b regs is issue-ordered)
                issue_b(level, woff + 16 + m, quad, bhp, bmp, blp, c2p, bh, bm, bl, c2v);
            #pragma unroll
            for (int i = 0; i < 4; ++i) {
                float dot = a0[i] + (a1[i] + a2[i]);      // same order as verified kernel
                float k = fmaf(-2.f, dot, c2cur);
                unsigned u = __float_as_uint(k);
                u = (u & 0x80000000u) ? ~u : (u | 0x80000000u);
                vkey[nt][i] = u;
            }
        }

        // ---- nt-merged argmin within 16-lane groups: 4 DPP chains + ballot pair ----
        #pragma unroll
        for (int i = 0; i < 4; ++i) {
            unsigned v0 = vkey[0][i], v1 = vkey[1][i];
            unsigned vm = v0 < v1 ? v0 : v1;
            unsigned r  = dpp_row_min16(vm);
            unsigned long long mk0 = __ballot(v0 == r);
            unsigned long long mk1 = __ballot(v1 == r);
            unsigned gg0 = (unsigned)(mk0 >> (quad * 16)) & 0xffffu;
            unsigned gg1 = (unsigned)(mk1 >> (quad * 16)) & 0xffffu;
            int bmin = woff + (gg0 ? __builtin_ctz(gg0) : 16 + __builtin_ctz(gg1));  // lowest tied bin
            if (m == 0)
                redw[quad * 4 + i][w] = ((unsigned long long)r << 32) | (unsigned)bmin;
        }
        __syncthreads();

        // prefetch next level's B(nt0): overlaps the serial reduce/update tail
        if (level + 1 < NQ)
            issue_b(level + 1, woff + m, quad, bhp, bmp, blp, c2p, bh, bm, bl, c2v);

        // ---- reduce 8 wave-results per row (broadcast b128 reads, 2 rows/wave) ----
        unsigned long long mn;
        {
            const ulonglong2* rp = (const ulonglong2*)&redw[rr_][0];
            ulonglong2 p0 = rp[0], p1 = rp[1], p2 = rp[2], p3 = rp[3];
            mn = u64min(u64min(u64min(p0.x, p0.y), u64min(p1.x, p1.y)),
                        u64min(u64min(p2.x, p2.y), u64min(p3.x, p3.y)));
        }
        const int wb = (int)(mn & 0xffffffffull);
        if (gd == 0)
            out_codes[(size_t)level * N + row0 + rr_] = (float)wb;

        // ---- fp32 residual update in registers (same arithmetic as reference) ----
        {
            const float4* cp = (const float4*)(cb_f32 + ((size_t)level * BINS + wb) * D + dbase);
            float4 c = *cp;
            rres[0] -= c.x; rres[1] -= c.y; rres[2] -= c.z; rres[3] -= c.w;
        }
        if (level + 1 < NQ)
            frag_store4(rres, ah, am, al, rr_, g8, half);   // next level's A
    }

    // ---- epilogue: quantized = hidden - residual ----
    {
        const float4* hp = (const float4*)(hidden + (size_t)(row0 + rr_) * D + dbase);
        float4 v = *hp;
        float4 q;
        q.x = v.x - rres[0]; q.y = v.y - rres[1]; q.z = v.z - rres[2]; q.w = v.w - rres[3];
        *(float4*)(out_quant + (size_t)(row0 + rr_) * D + dbase) = q;
    }
}

extern "C" void kernel_launch(void* const* d_in, const int* in_sizes, int n_in,
                              void* d_out, int out_size, void* d_ws, size_t ws_size,
                              hipStream_t stream) {
    const float* hidden    = (const float*)d_in[0];
    const float* codebooks = (const float*)d_in[1];
    float* out = (float*)d_out;
    const int N = in_sizes[0] / D;                 // 8192
    float* out_codes = out;                        // [NQ, N]
    float* out_quant = out + (size_t)NQ * N;       // [N, D]

    char* ws = (char*)d_ws;
    short* cb_hi  = (short*)ws;                    // 512 KB
    short* cb_mid = (short*)(ws +  512 * 1024);    // 512 KB
    short* cb_lo  = (short*)(ws + 1024 * 1024);    // 512 KB
    float* c2     = (float*)(ws + 1536 * 1024);    // 8 KB

    rvq_prep<<<dim3(NQ * 16), 256, 0, stream>>>(codebooks, cb_hi, cb_mid, cb_lo, c2);
    rvq_kernel<<<dim3(N / RPB), THREADS, 0, stream>>>(
        hidden, codebooks, cb_hi, cb_mid, cb_lo, c2, out_codes, out_quant, N);
}

// Round 3
// 102.467 us; speedup vs baseline: 1.2660x; 1.2660x over previous
//
#include <hip/hip_runtime.h>

#define NQ 8
#define BINS 256
#define D 128
#define RPB 32            // rows per block -> grid 256 = minimal B traffic (1 block/CU)
#define THREADS 1024      // 16 waves
#define RSTRIDE 132       // prep staging stride
#define FREG 520          // shorts per frag region (512 + 8 pad -> bank rotation)

typedef short s8v __attribute__((ext_vector_type(8)));   // 8 bf16 in 4 VGPRs
typedef short s4v __attribute__((ext_vector_type(4)));   // 4 bf16 in 2 VGPRs
typedef float f4v __attribute__((ext_vector_type(4)));   // MFMA accumulator

static __device__ __forceinline__ unsigned short bf16_rtne(float x) {
    unsigned u = __float_as_uint(x);
    unsigned r = (u + 0x7fffu + ((u >> 16) & 1u)) >> 16;
    return (unsigned short)r;
}
static __device__ __forceinline__ float bf16_to_f(unsigned short h) {
    return __uint_as_float(((unsigned)h) << 16);
}
struct Split3 { short h, m, l; };
static __device__ __forceinline__ Split3 split3(float x) {
    Split3 s;
    unsigned short hb = bf16_rtne(x);
    float r1 = x - bf16_to_f(hb);
    unsigned short mb = bf16_rtne(r1);
    unsigned short lb = bf16_rtne(r1 - bf16_to_f(mb));
    s.h = (short)hb; s.m = (short)mb; s.l = (short)lb;
    return s;
}
static __device__ __forceinline__ unsigned long long u64min(unsigned long long a, unsigned long long b) {
    return a < b ? a : b;
}
// min over the 16-lane DPP row (pure VALU): xor1, xor2 via quad_perm, then ror4, ror8
static __device__ __forceinline__ unsigned dpp_row_min16(unsigned v) {
    unsigned t;
    t = (unsigned)__builtin_amdgcn_update_dpp(0, (int)v, 0xB1,  0xF, 0xF, true); v = v < t ? v : t;
    t = (unsigned)__builtin_amdgcn_update_dpp(0, (int)v, 0x4E,  0xF, 0xF, true); v = v < t ? v : t;
    t = (unsigned)__builtin_amdgcn_update_dpp(0, (int)v, 0x124, 0xF, 0xF, true); v = v < t ? v : t;
    t = (unsigned)__builtin_amdgcn_update_dpp(0, (int)v, 0x128, 0xF, 0xF, true); v = v < t ? v : t;
    return v;
}

// ---- prep: codebooks fp32 -> bf16 3-way split (swizzled [L][kchunk][bin][8]) + ||c||^2 ----
__global__ __launch_bounds__(256) void rvq_prep(
    const float* __restrict__ cb, short* __restrict__ cb_hi,
    short* __restrict__ cb_mid, short* __restrict__ cb_lo,
    float* __restrict__ c2)
{
    __shared__ float st[16 * RSTRIDE];
    const int L = blockIdx.x >> 4;
    const int o = blockIdx.x & 15;
    const int t = threadIdx.x;

    const float4* src = (const float4*)(cb + ((size_t)L * BINS + o * 16) * D);
    #pragma unroll
    for (int i = 0; i < 2; ++i) {
        int f4 = i * 256 + t;
        int row = f4 >> 5, c4 = f4 & 31;
        float4 v = src[f4];
        float* d = &st[row * RSTRIDE + c4 * 4];
        d[0] = v.x; d[1] = v.y; d[2] = v.z; d[3] = v.w;
    }
    __syncthreads();

    const int bin = t >> 4;
    const int kc  = t & 15;
    const float* p = &st[bin * RSTRIDE + kc * 8];
    s8v h8, m8, l8;
    float s = 0.f;
    #pragma unroll
    for (int j = 0; j < 8; ++j) {
        float x = p[j];
        Split3 sp = split3(x);
        h8[j] = sp.h; m8[j] = sp.m; l8[j] = sp.l;
        s = fmaf(x, x, s);
    }
    int idx = (L * 16 + kc) * BINS + (o * 16 + bin);
    ((s8v*)cb_hi)[idx]  = h8;
    ((s8v*)cb_mid)[idx] = m8;
    ((s8v*)cb_lo)[idx]  = l8;
    s += __shfl_xor(s, 1, 64);
    s += __shfl_xor(s, 2, 64);
    s += __shfl_xor(s, 4, 64);
    s += __shfl_xor(s, 8, 64);
    if (kc == 0) c2[L * BINS + o * 16 + bin] = s;
}

// frag store: thread owns (row rr_, kchunk g8, half); region = mt*4 + ks.
// Bank math: dword = 260*(4mt+ks) + 4*idx16 + 2*half; per wave each bank gets 4
// dword-accesses (b64 minimum). Read side: 8 lanes per bank-quad (b128 minimum).
static __device__ __forceinline__ void frag_store4(
    const float* rres, short* ah, short* am, short* al, int rr_, int g8, int half)
{
    s4v h4, m4, l4;
    #pragma unroll
    for (int j = 0; j < 4; ++j) {
        Split3 sp = split3(rres[j]);
        h4[j] = sp.h; m4[j] = sp.m; l4[j] = sp.l;
    }
    int q  = g8 & 3;
    int ks = g8 >> 2;
    int mt = rr_ >> 4;
    int r16 = rr_ & 15;
    int idx16 = q * 16 + ((r16 + 4 * q) & 15);
    int off = (mt * 4 + ks) * FREG + idx16 * 8 + half * 4;
    *(s4v*)&ah[off] = h4;
    *(s4v*)&am[off] = m4;
    *(s4v*)&al[off] = l4;
}

static __device__ __forceinline__ void issue_b(
    int lv, int bin, int quad,
    const s8v* __restrict__ bhp, const s8v* __restrict__ bmp, const s8v* __restrict__ blp,
    const float* __restrict__ c2p,
    s8v bh[4], s8v bm[4], s8v bl[4], float& c2v)
{
    c2v = c2p[lv * BINS + bin];
    #pragma unroll
    for (int ks = 0; ks < 4; ++ks) {
        int idx = (lv * 16 + ks * 4 + quad) * BINS + bin;
        bh[ks] = bhp[idx];
        bm[ks] = bmp[idx];
        bl[ks] = blp[idx];
    }
}

// ---- main: 32 rows/block, 16 waves, wave owns a 16-bin window; residual in registers ----
__global__ __launch_bounds__(THREADS, 4) void rvq_kernel(
    const float* __restrict__ hidden,     // [N, D]
    const float* __restrict__ cb_f32,     // [NQ, BINS, D]
    const short* __restrict__ cb_hi,
    const short* __restrict__ cb_mid,
    const short* __restrict__ cb_lo,
    const float* __restrict__ c2p,        // [NQ, BINS]
    float* __restrict__ out_codes,        // [NQ, N] as float
    float* __restrict__ out_quant,        // [N, D]
    int N)
{
    __shared__ __align__(16) short ah[8 * FREG];
    __shared__ __align__(16) short am[8 * FREG];
    __shared__ __align__(16) short al[8 * FREG];
    __shared__ __align__(16) unsigned long long redw[RPB][18];  // 144B rows, 16B-aligned

    const int t = threadIdx.x;
    const int w = t >> 6;                 // wave 0..15
    const int l = t & 63;
    const int quad = l >> 4;
    const int m = l & 15;
    const int row0 = blockIdx.x * RPB;
    const int woff = w * 16;              // this wave's 16-bin window
    const int bin = woff + m;
    const int rr_  = t >> 5;              // owned row 0..31
    const int gd   = t & 31;
    const int g8   = gd >> 1;             // owned k-chunk 0..15
    const int half = gd & 1;
    const int dbase = g8 * 8 + half * 4;  // first owned dim

    // residual + hidden copy in registers: thread owns row rr_, dims [dbase, dbase+4)
    float rres[4], hreg[4];
    {
        const float4* hp = (const float4*)(hidden + (size_t)(row0 + rr_) * D + dbase);
        float4 v = *hp;
        hreg[0] = v.x; hreg[1] = v.y; hreg[2] = v.z; hreg[3] = v.w;
        rres[0] = v.x; rres[1] = v.y; rres[2] = v.z; rres[3] = v.w;
    }
    frag_store4(rres, ah, am, al, rr_, g8, half);

    const s8v* bhp = (const s8v*)cb_hi;
    const s8v* bmp = (const s8v*)cb_mid;
    const s8v* blp = (const s8v*)cb_lo;

    s8v bh[4], bm[4], bl[4];
    float c2v;
    issue_b(0, bin, quad, bhp, bmp, blp, c2p, bh, bm, bl, c2v);   // B(0) in flight

    for (int level = 0; level < NQ; ++level) {
        __syncthreads();   // frag stores visible; prefetched B drained by barrier's waitcnt

        // ---- MFMA: A loaded per-ks (3 live s8v -> no remat), B fully live ----
        unsigned ucand[2][4];
        const int idx16 = quad * 16 + ((m + 4 * quad) & 15);
        #pragma unroll
        for (int mt = 0; mt < 2; ++mt) {
            f4v a0 = {0.f, 0.f, 0.f, 0.f};   // hh
            f4v a1 = {0.f, 0.f, 0.f, 0.f};   // hm + mh
            f4v a2 = {0.f, 0.f, 0.f, 0.f};   // mm + hl + lh
            #pragma unroll
            for (int ks = 0; ks < 4; ++ks) {
                int off = (mt * 4 + ks) * FREG + idx16 * 8;
                s8v afh = *(const s8v*)&ah[off];
                s8v afm = *(const s8v*)&am[off];
                s8v afl = *(const s8v*)&al[off];
                a0 = __builtin_amdgcn_mfma_f32_16x16x32_bf16(afh, bh[ks], a0, 0, 0, 0);
                a1 = __builtin_amdgcn_mfma_f32_16x16x32_bf16(afh, bm[ks], a1, 0, 0, 0);
                a1 = __builtin_amdgcn_mfma_f32_16x16x32_bf16(afm, bh[ks], a1, 0, 0, 0);
                a2 = __builtin_amdgcn_mfma_f32_16x16x32_bf16(afm, bm[ks], a2, 0, 0, 0);
                a2 = __builtin_amdgcn_mfma_f32_16x16x32_bf16(afh, bl[ks], a2, 0, 0, 0);
                a2 = __builtin_amdgcn_mfma_f32_16x16x32_bf16(afl, bh[ks], a2, 0, 0, 0);
            }
            #pragma unroll
            for (int i = 0; i < 4; ++i) {
                float dot = a0[i] + (a1[i] + a2[i]);      // same order as verified kernel
                float k = fmaf(-2.f, dot, c2v);
                unsigned u = __float_as_uint(k);
                u = (u & 0x80000000u) ? ~u : (u | 0x80000000u);
                ucand[mt][i] = u;
            }
        }

        // prefetch next level's B right after last use: hides L2 stream under
        // argmin + reduce + update + barrier
        if (level + 1 < NQ)
            issue_b(level + 1, bin, quad, bhp, bmp, blp, c2p, bh, bm, bl, c2v);

        // ---- argmin within 16-lane groups: DPP min + ballot (lowest tied bin) ----
        #pragma unroll
        for (int mt = 0; mt < 2; ++mt)
            #pragma unroll
            for (int i = 0; i < 4; ++i) {
                unsigned v = ucand[mt][i];
                unsigned r = dpp_row_min16(v);
                unsigned long long mk = __ballot(v == r);
                unsigned grp = (unsigned)(mk >> (quad * 16)) & 0xffffu;
                int bmin = woff + __builtin_ctz(grp);
                if (m == 0)
                    redw[mt * 16 + quad * 4 + i][w] =
                        ((unsigned long long)r << 32) | (unsigned)bmin;
            }
        __syncthreads();

        // ---- reduce 16 wave-results per row (broadcast b128 reads) ----
        unsigned long long mn;
        {
            const ulonglong2* rp = (const ulonglong2*)&redw[rr_][0];
            ulonglong2 p0 = rp[0], p1 = rp[1], p2 = rp[2], p3 = rp[3];
            ulonglong2 p4 = rp[4], p5 = rp[5], p6 = rp[6], p7 = rp[7];
            unsigned long long a = u64min(u64min(u64min(p0.x, p0.y), u64min(p1.x, p1.y)),
                                          u64min(u64min(p2.x, p2.y), u64min(p3.x, p3.y)));
            unsigned long long b = u64min(u64min(u64min(p4.x, p4.y), u64min(p5.x, p5.y)),
                                          u64min(u64min(p6.x, p6.y), u64min(p7.x, p7.y)));
            mn = u64min(a, b);
        }
        const int wb = (int)(mn & 0xffffffffull);
        if (gd == 0)
            out_codes[(size_t)level * N + row0 + rr_] = (float)wb;

        // ---- fp32 residual update in registers (same arithmetic as reference) ----
        {
            const float4* cp = (const float4*)(cb_f32 + ((size_t)level * BINS + wb) * D + dbase);
            float4 c = *cp;
            rres[0] -= c.x; rres[1] -= c.y; rres[2] -= c.z; rres[3] -= c.w;
        }
        if (level + 1 < NQ)
            frag_store4(rres, ah, am, al, rr_, g8, half);   // next level's A
    }

    // ---- epilogue: quantized = hidden - residual (hidden kept in registers) ----
    {
        float4 q;
        q.x = hreg[0] - rres[0]; q.y = hreg[1] - rres[1];
        q.z = hreg[2] - rres[2]; q.w = hreg[3] - rres[3];
        *(float4*)(out_quant + (size_t)(row0 + rr_) * D + dbase) = q;
    }
}

extern "C" void kernel_launch(void* const* d_in, const int* in_sizes, int n_in,
                              void* d_out, int out_size, void* d_ws, size_t ws_size,
                              hipStream_t stream) {
    const float* hidden    = (const float*)d_in[0];
    const float* codebooks = (const float*)d_in[1];
    float* out = (float*)d_out;
    const int N = in_sizes[0] / D;                 // 8192
    float* out_codes = out;                        // [NQ, N]
    float* out_quant = out + (size_t)NQ * N;       // [N, D]

    char* ws = (char*)d_ws;
    short* cb_hi  = (short*)ws;                    // 512 KB
    short* cb_mid = (short*)(ws +  512 * 1024);    // 512 KB
    short* cb_lo  = (short*)(ws + 1024 * 1024);    // 512 KB
    float* c2     = (float*)(ws + 1536 * 1024);    // 8 KB

    rvq_prep<<<dim3(NQ * 16), 256, 0, stream>>>(codebooks, cb_hi, cb_mid, cb_lo, c2);
    rvq_kernel<<<dim3(N / RPB), THREADS, 0, stream>>>(
        hidden, codebooks, cb_hi, cb_mid, cb_lo, c2, out_codes, out_quant, N);
}